// Round 1
// 953.152 us; speedup vs baseline: 1.0609x; 1.0609x over previous
//
#include <hip/hip_runtime.h>

typedef _Float16 f16x8 __attribute__((ext_vector_type(8)));
typedef float f32x4 __attribute__((ext_vector_type(4)));

#define EPS 1e-5f

__device__ __forceinline__ short f2h(float x) {
    _Float16 h = (_Float16)x;   // round-to-nearest-even v_cvt_f16_f32
    union { _Float16 h; short s; } u;
    u.h = h;
    return u.s;
}

// ---------------------------------------------------------------------------
// prep: transpose+convert Wm -> WtM[l][f][k] fp16, Wl -> WtF[f][k] fp16 (f padded
// to 48 with zeros), zero the stats buffers. Runs every call (ws is re-poisoned).
// ---------------------------------------------------------------------------
__global__ void prep_kernel(const float* __restrict__ Wm, const float* __restrict__ Wl,
                            short* __restrict__ WtM, short* __restrict__ WtF,
                            float* __restrict__ stats) {
    const long T1 = 14L * 896 * 128;
    const long T2 = 48L * 896;
    const long T3 = 15L * 256;
    long i = (long)blockIdx.x * blockDim.x + threadIdx.x;
    if (i < T1) {
        long l = i / (896 * 128);
        long r = i % (896 * 128);
        long k = r >> 7;
        long f = r & 127;
        WtM[l * 114688 + f * 896 + k] = f2h(Wm[i]);
    } else if (i < T1 + T2) {
        long j = i - T1;
        long f = j / 896;
        long k = j % 896;
        WtF[j] = (f < 36) ? f2h(Wl[k * 36 + f]) : (short)0;
    } else if (i < T1 + T2 + T3) {
        stats[i - T1 - T2] = 0.0f;
    }
}

// ---------------------------------------------------------------------------
// layer0: h_lin[n,f] = b0[f] + sum_{k<21} x[idx[n,k/3], k%3] * W0[k,f]
// plus per-feature sum / sumsq accumulation.
// Restructured: 256 threads, 16 nodes per tile (1 barrier pair per 16 nodes,
// not per node), grid-stride over tiles. thread = (feat = tid&127, half = tid>>7),
// each (feat,half) computes 8 nodes of the tile. All fp32 — exact, same fma order
// as before.
// ---------------------------------------------------------------------------
#define L0_NB 16
__global__ __launch_bounds__(256) void layer0_kernel(
        const float* __restrict__ x, const int* __restrict__ idx,
        const float* __restrict__ W0, const float* __restrict__ b0,
        float* __restrict__ hlin, float* __restrict__ stats, int N) {
    __shared__ float sW[21 * 128];
    __shared__ float sX[L0_NB * 21];
    __shared__ float sStat[256];
    const int tid = threadIdx.x;
    for (int i = tid; i < 21 * 128; i += 256) sW[i] = W0[i];
    const int f = tid & 127;
    const int half = tid >> 7;
    const float bf = b0[f];
    float s = 0.f, ss = 0.f;
    const int ntiles = (N + L0_NB - 1) / L0_NB;
    for (int t = blockIdx.x; t < ntiles; t += gridDim.x) {
        const int n0 = t * L0_NB;
        __syncthreads();
        for (int i = tid; i < L0_NB * 21; i += 256) {
            int ni = i / 21;
            int k = i - ni * 21;
            int j = k / 3;
            int c = k - j * 3;
            int n = n0 + ni;
            if (n >= N) n = N - 1;
            sX[i] = x[(long)idx[n * 7 + j] * 3 + c];
        }
        __syncthreads();
#pragma unroll
        for (int ni = 0; ni < 8; ++ni) {
            int node = n0 + half * 8 + ni;
            if (node >= N) break;   // per-thread, no barrier inside
            float acc = bf;
#pragma unroll
            for (int k = 0; k < 21; ++k)
                acc = fmaf(sX[(half * 8 + ni) * 21 + k], sW[k * 128 + f], acc);
            hlin[(long)node * 128 + f] = acc;
            s += acc;
            ss += acc * acc;
        }
    }
    // block-level reduce across the two halves, then one atomic pair per feature
    __syncthreads();
    if (half == 1) { sStat[f] = s; sStat[128 + f] = ss; }
    __syncthreads();
    if (half == 0) {
        atomicAdd(&stats[f], s + sStat[f]);
        atomicAdd(&stats[128 + f], ss + sStat[128 + f]);
    }
}

// ---------------------------------------------------------------------------
// gemm_mid (BN-fused): input = relu(bn(hprev)) computed on the fly during the
// A-gather staging (sc/sh folded from statsIn + g/be, held in 16 registers —
// per-thread feature block is fixed because the staging stride is 256).
// Output: hlin fp32 (pre-BN) + per-feature sum/sumsq stats.
// Block: 256 thr = 4 waves, tile 64 nodes x 128 feats; wave = 32 nodes x 64 feats
// (2x4 subtiles of 16x16, mfma_f32_16x16x32_f16).
// LDS pad +8 shorts per row: lane stride 272B -> <=2-way bank aliasing (free).
// sAux (256 f32) holds sc|sh during staging, is reused as the stats scratch in
// the epilogue -> LDS stays at 53,248 B -> 3 blocks/CU preserved.
// ---------------------------------------------------------------------------
__global__ __launch_bounds__(256, 3) void gemm_mid_kernel(
        const float* __restrict__ hprev, const int* __restrict__ idx,
        const short* __restrict__ Wt, const float* __restrict__ bvec,
        const float* __restrict__ g, const float* __restrict__ be,
        const float* __restrict__ statsIn,
        float* __restrict__ hlin, float* __restrict__ statsOut,
        int N, float invN) {
    __shared__ short sA[64 * 136];   // [node][k] for current j
    __shared__ short sB[128 * 136];  // [feat][k] for current j
    __shared__ float sAux[256];      // sc|sh during staging; stats scratch at epilogue

    const int tid = threadIdx.x;
    const int wave = tid >> 6;
    const int lane = tid & 63;
    const int quad = lane >> 4;
    const int l16 = lane & 15;
    const int wm = wave & 1;        // node half (32 nodes)
    const int wf = wave >> 1;       // feat half (64 feats)
    const int m0 = blockIdx.x * 64;
    const int fb = (tid & 15) * 8;  // fixed gathered-feature block for this thread

    if (tid < 128) {
        float mu = statsIn[tid] * invN;
        float var = statsIn[128 + tid] * invN - mu * mu;
        float rs = rsqrtf(var + EPS);
        float sc = g[tid] * rs;
        sAux[tid] = sc;
        sAux[128 + tid] = be[tid] - mu * sc;
    }
    __syncthreads();
    float scR[8], shR[8];
#pragma unroll
    for (int e = 0; e < 8; ++e) {
        scR[e] = sAux[fb + e];
        shR[e] = sAux[128 + fb + e];
    }

    f32x4 acc[2][4];
#pragma unroll
    for (int ni = 0; ni < 4; ++ni) {
        float bv = bvec[wf * 64 + ni * 16 + l16];
#pragma unroll
        for (int mi = 0; mi < 2; ++mi) {
            acc[mi][ni][0] = bv; acc[mi][ni][1] = bv; acc[mi][ni][2] = bv; acc[mi][ni][3] = bv;
        }
    }

    for (int j = 0; j < 7; ++j) {
        __syncthreads();
        // stage B: 128 feats x 128 k  (2048 chunks of 8 fp16)
#pragma unroll
        for (int i = tid; i < 2048; i += 256) {
            int ff = i >> 4, ch = i & 15;
            *(f16x8*)&sB[ff * 136 + ch * 8] =
                *(const f16x8*)&Wt[(long)ff * 896 + j * 128 + ch * 8];
        }
        // stage A: 64 nodes x 128 k (gathered fp32 rows, BN+ReLU+f16 applied inline)
#pragma unroll
        for (int i = tid; i < 1024; i += 256) {
            int nl = i >> 4;                 // i & 15 == tid & 15 -> fb fixed
            int n = m0 + nl;
            n = (n < N) ? n : (N - 1);
            long row = idx[n * 7 + j];
            const float* src = &hprev[row * 128 + fb];
            float4 v0 = *(const float4*)src;
            float4 v1 = *(const float4*)(src + 4);
            union { short sh8[8]; f16x8 v; } u;
            u.sh8[0] = f2h(fmaxf(fmaf(v0.x, scR[0], shR[0]), 0.f));
            u.sh8[1] = f2h(fmaxf(fmaf(v0.y, scR[1], shR[1]), 0.f));
            u.sh8[2] = f2h(fmaxf(fmaf(v0.z, scR[2], shR[2]), 0.f));
            u.sh8[3] = f2h(fmaxf(fmaf(v0.w, scR[3], shR[3]), 0.f));
            u.sh8[4] = f2h(fmaxf(fmaf(v1.x, scR[4], shR[4]), 0.f));
            u.sh8[5] = f2h(fmaxf(fmaf(v1.y, scR[5], shR[5]), 0.f));
            u.sh8[6] = f2h(fmaxf(fmaf(v1.z, scR[6], shR[6]), 0.f));
            u.sh8[7] = f2h(fmaxf(fmaf(v1.w, scR[7], shR[7]), 0.f));
            *(f16x8*)&sA[nl * 136 + fb] = u.v;
        }
        __syncthreads();
#pragma unroll
        for (int k0 = 0; k0 < 128; k0 += 32) {
            f16x8 a[2], b[4];
#pragma unroll
            for (int mi = 0; mi < 2; ++mi)
                a[mi] = *(const f16x8*)&sA[(wm * 32 + mi * 16 + l16) * 136 + k0 + quad * 8];
#pragma unroll
            for (int ni = 0; ni < 4; ++ni)
                b[ni] = *(const f16x8*)&sB[(wf * 64 + ni * 16 + l16) * 136 + k0 + quad * 8];
#pragma unroll
            for (int mi = 0; mi < 2; ++mi)
#pragma unroll
                for (int ni = 0; ni < 4; ++ni)
                    acc[mi][ni] = __builtin_amdgcn_mfma_f32_16x16x32_f16(a[mi], b[ni], acc[mi][ni], 0, 0, 0);
        }
    }

    // epilogue: store h_lin fp32, accumulate per-feature stats (sAux reused)
    __syncthreads();
    sAux[tid] = 0.f;
    __syncthreads();
#pragma unroll
    for (int mi = 0; mi < 2; ++mi) {
#pragma unroll
        for (int ni = 0; ni < 4; ++ni) {
            int feat = wf * 64 + ni * 16 + l16;
            float s = 0.f, ss = 0.f;
#pragma unroll
            for (int r = 0; r < 4; ++r) {
                int node = m0 + wm * 32 + mi * 16 + quad * 4 + r;
                float v = acc[mi][ni][r];
                if (node < N) {
                    hlin[(long)node * 128 + feat] = v;
                    s += v;
                    ss += v * v;
                }
            }
            atomicAdd(&sAux[feat], s);
            atomicAdd(&sAux[128 + feat], ss);
        }
    }
    __syncthreads();
    if (tid < 128) {
        atomicAdd(&statsOut[tid], sAux[tid]);
        atomicAdd(&statsOut[128 + tid], sAux[128 + tid]);
    }
}

// ---------------------------------------------------------------------------
// gemm_final (BN-fused): out[N,36] = gather7(relu(bn(hprev)))[N,896] @ Wl + bl
// WtF: [48][896] fp16 (feats 36..47 zero). Block: 64 nodes, wave = 16 nodes x 48 feats.
// ---------------------------------------------------------------------------
__global__ __launch_bounds__(256) void gemm_final_kernel(
        const float* __restrict__ hprev, const int* __restrict__ idx,
        const short* __restrict__ WtF, const float* __restrict__ bl,
        const float* __restrict__ g, const float* __restrict__ be,
        const float* __restrict__ statsIn,
        float* __restrict__ out, int N, float invN) {
    __shared__ short sA[64 * 136];
    __shared__ short sB[48 * 136];
    __shared__ float sAux[256];

    const int tid = threadIdx.x;
    const int wave = tid >> 6;
    const int lane = tid & 63;
    const int quad = lane >> 4;
    const int l16 = lane & 15;
    const int m0 = blockIdx.x * 64;
    const int fb = (tid & 15) * 8;

    if (tid < 128) {
        float mu = statsIn[tid] * invN;
        float var = statsIn[128 + tid] * invN - mu * mu;
        float rs = rsqrtf(var + EPS);
        float sc = g[tid] * rs;
        sAux[tid] = sc;
        sAux[128 + tid] = be[tid] - mu * sc;
    }
    __syncthreads();
    float scR[8], shR[8];
#pragma unroll
    for (int e = 0; e < 8; ++e) {
        scR[e] = sAux[fb + e];
        shR[e] = sAux[128 + fb + e];
    }

    f32x4 acc[3];
#pragma unroll
    for (int ni = 0; ni < 3; ++ni) {
        int feat = ni * 16 + l16;
        float bv = (feat < 36) ? bl[feat] : 0.f;
        acc[ni][0] = bv; acc[ni][1] = bv; acc[ni][2] = bv; acc[ni][3] = bv;
    }

    for (int j = 0; j < 7; ++j) {
        __syncthreads();
#pragma unroll
        for (int i = tid; i < 768; i += 256) {
            int ff = i >> 4, ch = i & 15;
            *(f16x8*)&sB[ff * 136 + ch * 8] =
                *(const f16x8*)&WtF[(long)ff * 896 + j * 128 + ch * 8];
        }
#pragma unroll
        for (int i = tid; i < 1024; i += 256) {
            int nl = i >> 4;
            int n = m0 + nl;
            n = (n < N) ? n : (N - 1);
            long row = idx[n * 7 + j];
            const float* src = &hprev[row * 128 + fb];
            float4 v0 = *(const float4*)src;
            float4 v1 = *(const float4*)(src + 4);
            union { short sh8[8]; f16x8 v; } u;
            u.sh8[0] = f2h(fmaxf(fmaf(v0.x, scR[0], shR[0]), 0.f));
            u.sh8[1] = f2h(fmaxf(fmaf(v0.y, scR[1], shR[1]), 0.f));
            u.sh8[2] = f2h(fmaxf(fmaf(v0.z, scR[2], shR[2]), 0.f));
            u.sh8[3] = f2h(fmaxf(fmaf(v0.w, scR[3], shR[3]), 0.f));
            u.sh8[4] = f2h(fmaxf(fmaf(v1.x, scR[4], shR[4]), 0.f));
            u.sh8[5] = f2h(fmaxf(fmaf(v1.y, scR[5], shR[5]), 0.f));
            u.sh8[6] = f2h(fmaxf(fmaf(v1.z, scR[6], shR[6]), 0.f));
            u.sh8[7] = f2h(fmaxf(fmaf(v1.w, scR[7], shR[7]), 0.f));
            *(f16x8*)&sA[nl * 136 + fb] = u.v;
        }
        __syncthreads();
#pragma unroll
        for (int k0 = 0; k0 < 128; k0 += 32) {
            f16x8 a = *(const f16x8*)&sA[(wave * 16 + l16) * 136 + k0 + quad * 8];
            f16x8 b[3];
#pragma unroll
            for (int ni = 0; ni < 3; ++ni)
                b[ni] = *(const f16x8*)&sB[(ni * 16 + l16) * 136 + k0 + quad * 8];
#pragma unroll
            for (int ni = 0; ni < 3; ++ni)
                acc[ni] = __builtin_amdgcn_mfma_f32_16x16x32_f16(a, b[ni], acc[ni], 0, 0, 0);
        }
    }

#pragma unroll
    for (int ni = 0; ni < 3; ++ni) {
        int feat = ni * 16 + l16;
        if (feat < 36) {
#pragma unroll
            for (int r = 0; r < 4; ++r) {
                int node = m0 + wave * 16 + quad * 4 + r;
                if (node < N) out[(long)node * 36 + feat] = acc[ni][r];
            }
        }
    }
}

// ---------------------------------------------------------------------------
extern "C" void kernel_launch(void* const* d_in, const int* in_sizes, int n_in,
                              void* d_out, int out_size, void* d_ws, size_t ws_size,
                              hipStream_t stream) {
    const float* x   = (const float*)d_in[0];
    const int*   idx = (const int*)d_in[1];
    const float* W0  = (const float*)d_in[2];
    const float* b0  = (const float*)d_in[3];
    const float* g0  = (const float*)d_in[4];
    const float* be0 = (const float*)d_in[5];
    const float* Wm  = (const float*)d_in[6];
    const float* bm  = (const float*)d_in[7];
    const float* gm  = (const float*)d_in[8];
    const float* bem = (const float*)d_in[9];
    const float* Wl  = (const float*)d_in[10];
    const float* bl  = (const float*)d_in[11];
    float* out = (float*)d_out;

    const int N = in_sizes[0] / 3;          // 40962
    const float invN = 1.0f / (float)N;

    char* ws = (char*)d_ws;
    size_t off = 0;
    auto alloc = [&](size_t bytes) -> void* {
        void* p = ws + off;
        off = (off + bytes + 255) & ~(size_t)255;
        return p;
    };
    short* WtM   = (short*)alloc(14UL * 128 * 896 * 2);
    short* WtF   = (short*)alloc(48UL * 896 * 2);
    float* stats = (float*)alloc(15UL * 256 * 4);
    float* hlinA = (float*)alloc((size_t)N * 128 * 4);
    float* hlinB = (float*)alloc((size_t)N * 128 * 4);

    {
        long total = 14L * 896 * 128 + 48L * 896 + 15L * 256;
        int blocks = (int)((total + 255) / 256);
        prep_kernel<<<blocks, 256, 0, stream>>>(Wm, Wl, WtM, WtF, stats);
    }

    layer0_kernel<<<1280, 256, 0, stream>>>(x, idx, W0, b0, hlinA, stats, N);

    const int gblocks = (N + 63) / 64;
    float* hin = hlinA;
    float* hout = hlinB;
    const float* gPrev = g0;
    const float* bePrev = be0;
    for (int L = 0; L < 14; ++L) {
        gemm_mid_kernel<<<gblocks, 256, 0, stream>>>(
            hin, idx, WtM + (size_t)L * 128 * 896, bm + L * 128,
            gPrev, bePrev, stats + L * 256,
            hout, stats + (L + 1) * 256, N, invN);
        gPrev = gm + L * 128;
        bePrev = bem + L * 128;
        float* t = hin; hin = hout; hout = t;
    }

    gemm_final_kernel<<<gblocks, 256, 0, stream>>>(
        hin, idx, WtF, bl, gm + 13 * 128, bem + 13 * 128, stats + 14 * 256,
        out, N, invN);
}

// Round 2
// 810.931 us; speedup vs baseline: 1.2469x; 1.1754x over previous
//
#include <hip/hip_runtime.h>

typedef _Float16 f16x8 __attribute__((ext_vector_type(8)));
typedef float f32x4 __attribute__((ext_vector_type(4)));

#define EPS 1e-5f

__device__ __forceinline__ short f2h(float x) {
    _Float16 h = (_Float16)x;   // round-to-nearest-even v_cvt_f16_f32
    union { _Float16 h; short s; } u;
    u.h = h;
    return u.s;
}

// ---------------------------------------------------------------------------
// prep: transpose+convert Wm -> WtM[l][f][k] fp16, Wl -> WtF[f][k] fp16 (f padded
// to 48 with zeros), zero the stats buffers. Runs every call (ws is re-poisoned).
// ---------------------------------------------------------------------------
__global__ void prep_kernel(const float* __restrict__ Wm, const float* __restrict__ Wl,
                            short* __restrict__ WtM, short* __restrict__ WtF,
                            float* __restrict__ stats) {
    const long T1 = 14L * 896 * 128;
    const long T2 = 48L * 896;
    const long T3 = 15L * 256;
    long i = (long)blockIdx.x * blockDim.x + threadIdx.x;
    if (i < T1) {
        long l = i / (896 * 128);
        long r = i % (896 * 128);
        long k = r >> 7;
        long f = r & 127;
        WtM[l * 114688 + f * 896 + k] = f2h(Wm[i]);
    } else if (i < T1 + T2) {
        long j = i - T1;
        long f = j / 896;
        long k = j % 896;
        WtF[j] = (f < 36) ? f2h(Wl[k * 36 + f]) : (short)0;
    } else if (i < T1 + T2 + T3) {
        stats[i - T1 - T2] = 0.0f;
    }
}

// ---------------------------------------------------------------------------
// layer0: h_lin[n,f] = b0[f] + sum_{k<21} x[idx[n,k/3], k%3] * W0[k,f]
// plus per-feature sum / sumsq accumulation. 16-node tiles, 1 barrier pair per
// tile. All fp32 — exact.
// ---------------------------------------------------------------------------
#define L0_NB 16
__global__ __launch_bounds__(256) void layer0_kernel(
        const float* __restrict__ x, const int* __restrict__ idx,
        const float* __restrict__ W0, const float* __restrict__ b0,
        float* __restrict__ hlin, float* __restrict__ stats, int N) {
    __shared__ float sW[21 * 128];
    __shared__ float sX[L0_NB * 21];
    __shared__ float sStat[256];
    const int tid = threadIdx.x;
    for (int i = tid; i < 21 * 128; i += 256) sW[i] = W0[i];
    const int f = tid & 127;
    const int half = tid >> 7;
    const float bf = b0[f];
    float s = 0.f, ss = 0.f;
    const int ntiles = (N + L0_NB - 1) / L0_NB;
    for (int t = blockIdx.x; t < ntiles; t += gridDim.x) {
        const int n0 = t * L0_NB;
        __syncthreads();
        for (int i = tid; i < L0_NB * 21; i += 256) {
            int ni = i / 21;
            int k = i - ni * 21;
            int j = k / 3;
            int c = k - j * 3;
            int n = n0 + ni;
            if (n >= N) n = N - 1;
            sX[i] = x[(long)idx[n * 7 + j] * 3 + c];
        }
        __syncthreads();
#pragma unroll
        for (int ni = 0; ni < 8; ++ni) {
            int node = n0 + half * 8 + ni;
            if (node >= N) break;   // per-thread, no barrier inside
            float acc = bf;
#pragma unroll
            for (int k = 0; k < 21; ++k)
                acc = fmaf(sX[(half * 8 + ni) * 21 + k], sW[k * 128 + f], acc);
            hlin[(long)node * 128 + f] = acc;
            s += acc;
            ss += acc * acc;
        }
    }
    __syncthreads();
    if (half == 1) { sStat[f] = s; sStat[128 + f] = ss; }
    __syncthreads();
    if (half == 0) {
        atomicAdd(&stats[f], s + sStat[f]);
        atomicAdd(&stats[128 + f], ss + sStat[128 + f]);
    }
}

// ---------------------------------------------------------------------------
// gemm_mid (BN-fused, software-pipelined):
//   input = relu(bn(hprev)) computed on the fly during A staging.
//   Pipeline (T14 issue-early/write-late): registers av/bv hold the j+1 tile,
//   issued BEFORE the MFMA phase of tile j so the gather latency (idx -> random
//   hprev row, ~600-1100cy) hides under MFMA + next write phase, instead of
//   serializing between the two barriers.
// Block: 256 thr = 4 waves, tile 64 nodes x 128 feats; wave = 32 nodes x 64 feats.
// LDS 53,248 B -> 3 blocks/CU; VGPR budget ~165 < 170 (=512/3) so occupancy holds.
// ---------------------------------------------------------------------------
__global__ __launch_bounds__(256, 3) void gemm_mid_kernel(
        const float* __restrict__ hprev, const int* __restrict__ idx,
        const short* __restrict__ Wt, const float* __restrict__ bvec,
        const float* __restrict__ g, const float* __restrict__ be,
        const float* __restrict__ statsIn,
        float* __restrict__ hlin, float* __restrict__ statsOut,
        int N, float invN) {
    __shared__ short sA[64 * 136];   // [node][k] for current j
    __shared__ short sB[128 * 136];  // [feat][k] for current j
    __shared__ float sAux[256];      // sc|sh during staging; stats scratch at epilogue

    const int tid = threadIdx.x;
    const int wave = tid >> 6;
    const int lane = tid & 63;
    const int quad = lane >> 4;
    const int l16 = lane & 15;
    const int wm = wave & 1;        // node half (32 nodes)
    const int wf = wave >> 1;       // feat half (64 feats)
    const int m0 = blockIdx.x * 64;
    const int t16 = tid >> 4;       // 0..15: node/feat row group for staging
    const int fb = (tid & 15) * 8;  // fixed k/feature chunk for staging

    if (tid < 128) {
        float mu = statsIn[tid] * invN;
        float var = statsIn[128 + tid] * invN - mu * mu;
        float rs = rsqrtf(var + EPS);
        float sc = g[tid] * rs;
        sAux[tid] = sc;
        sAux[128 + tid] = be[tid] - mu * sc;
    }
    __syncthreads();
    float scR[8], shR[8];
#pragma unroll
    for (int e = 0; e < 8; ++e) {
        scR[e] = sAux[fb + e];
        shR[e] = sAux[128 + fb + e];
    }

    f32x4 acc[2][4];
#pragma unroll
    for (int ni = 0; ni < 4; ++ni) {
        float bv = bvec[wf * 64 + ni * 16 + l16];
#pragma unroll
        for (int mi = 0; mi < 2; ++mi) {
            acc[mi][ni][0] = bv; acc[mi][ni][1] = bv; acc[mi][ni][2] = bv; acc[mi][ni][3] = bv;
        }
    }

    float4 av[8];   // A prefetch: 4 chunks x 2 float4 (gathered fp32 rows)
    f16x8 bv[8];    // B prefetch: 8 chunks of 8 fp16

    // --- issue loads for tile j into av/bv -------------------------------
    auto issueA = [&](int j) {
#pragma unroll
        for (int it = 0; it < 4; ++it) {
            int nl = t16 + it * 16;
            int n = m0 + nl;
            n = (n < N) ? n : (N - 1);
            long row = idx[n * 7 + j];
            const float* src = &hprev[row * 128 + fb];
            av[2 * it]     = *(const float4*)src;
            av[2 * it + 1] = *(const float4*)(src + 4);
        }
    };
    auto issueB = [&](int j) {
#pragma unroll
        for (int it = 0; it < 8; ++it) {
            int ff = t16 + it * 16;
            bv[it] = *(const f16x8*)&Wt[(long)ff * 896 + j * 128 + fb];
        }
    };
    // --- consume av/bv -> LDS (BN+ReLU+f16 on A) -------------------------
    auto writeA = [&]() {
#pragma unroll
        for (int it = 0; it < 4; ++it) {
            int nl = t16 + it * 16;
            float4 v0 = av[2 * it], v1 = av[2 * it + 1];
            union { short sh8[8]; f16x8 v; } u;
            u.sh8[0] = f2h(fmaxf(fmaf(v0.x, scR[0], shR[0]), 0.f));
            u.sh8[1] = f2h(fmaxf(fmaf(v0.y, scR[1], shR[1]), 0.f));
            u.sh8[2] = f2h(fmaxf(fmaf(v0.z, scR[2], shR[2]), 0.f));
            u.sh8[3] = f2h(fmaxf(fmaf(v0.w, scR[3], shR[3]), 0.f));
            u.sh8[4] = f2h(fmaxf(fmaf(v1.x, scR[4], shR[4]), 0.f));
            u.sh8[5] = f2h(fmaxf(fmaf(v1.y, scR[5], shR[5]), 0.f));
            u.sh8[6] = f2h(fmaxf(fmaf(v1.z, scR[6], shR[6]), 0.f));
            u.sh8[7] = f2h(fmaxf(fmaf(v1.w, scR[7], shR[7]), 0.f));
            *(f16x8*)&sA[nl * 136 + fb] = u.v;
        }
    };
    auto writeB = [&]() {
#pragma unroll
        for (int it = 0; it < 8; ++it) {
            int ff = t16 + it * 16;
            *(f16x8*)&sB[ff * 136 + fb] = bv[it];
        }
    };

    issueB(0);
    issueA(0);

    for (int j = 0; j < 7; ++j) {
        __syncthreads();            // sA/sB free (previous MFMA done)
        writeB();                   // implicit vmcnt waits at first use
        writeA();
        if (j < 6) {                // issue j+1 BEFORE compute of j
            issueB(j + 1);
            issueA(j + 1);
        }
        __syncthreads();
#pragma unroll
        for (int k0 = 0; k0 < 128; k0 += 32) {
            f16x8 a[2], b[4];
#pragma unroll
            for (int mi = 0; mi < 2; ++mi)
                a[mi] = *(const f16x8*)&sA[(wm * 32 + mi * 16 + l16) * 136 + k0 + quad * 8];
#pragma unroll
            for (int ni = 0; ni < 4; ++ni)
                b[ni] = *(const f16x8*)&sB[(wf * 64 + ni * 16 + l16) * 136 + k0 + quad * 8];
#pragma unroll
            for (int mi = 0; mi < 2; ++mi)
#pragma unroll
                for (int ni = 0; ni < 4; ++ni)
                    acc[mi][ni] = __builtin_amdgcn_mfma_f32_16x16x32_f16(a[mi], b[ni], acc[mi][ni], 0, 0, 0);
        }
    }

    // epilogue: store h_lin fp32, accumulate per-feature stats (sAux reused)
    __syncthreads();
    sAux[tid] = 0.f;
    __syncthreads();
#pragma unroll
    for (int mi = 0; mi < 2; ++mi) {
#pragma unroll
        for (int ni = 0; ni < 4; ++ni) {
            int feat = wf * 64 + ni * 16 + l16;
            float s = 0.f, ss = 0.f;
#pragma unroll
            for (int r = 0; r < 4; ++r) {
                int node = m0 + wm * 32 + mi * 16 + quad * 4 + r;
                float v = acc[mi][ni][r];
                if (node < N) {
                    hlin[(long)node * 128 + feat] = v;
                    s += v;
                    ss += v * v;
                }
            }
            atomicAdd(&sAux[feat], s);
            atomicAdd(&sAux[128 + feat], ss);
        }
    }
    __syncthreads();
    if (tid < 128) {
        atomicAdd(&statsOut[tid], sAux[tid]);
        atomicAdd(&statsOut[128 + tid], sAux[128 + tid]);
    }
}

// ---------------------------------------------------------------------------
// gemm_final (BN-fused, software-pipelined like gemm_mid):
//   out[N,36] = gather7(relu(bn(hprev)))[N,896] @ Wl + bl
// WtF: [48][896] fp16 (feats 36..47 zero). Block: 64 nodes, wave = 16 nodes x 48 feats.
// ---------------------------------------------------------------------------
__global__ __launch_bounds__(256) void gemm_final_kernel(
        const float* __restrict__ hprev, const int* __restrict__ idx,
        const short* __restrict__ WtF, const float* __restrict__ bl,
        const float* __restrict__ g, const float* __restrict__ be,
        const float* __restrict__ statsIn,
        float* __restrict__ out, int N, float invN) {
    __shared__ short sA[64 * 136];
    __shared__ short sB[48 * 136];
    __shared__ float sAux[256];

    const int tid = threadIdx.x;
    const int wave = tid >> 6;
    const int lane = tid & 63;
    const int quad = lane >> 4;
    const int l16 = lane & 15;
    const int m0 = blockIdx.x * 64;
    const int t16 = tid >> 4;
    const int fb = (tid & 15) * 8;

    if (tid < 128) {
        float mu = statsIn[tid] * invN;
        float var = statsIn[128 + tid] * invN - mu * mu;
        float rs = rsqrtf(var + EPS);
        float sc = g[tid] * rs;
        sAux[tid] = sc;
        sAux[128 + tid] = be[tid] - mu * sc;
    }
    __syncthreads();
    float scR[8], shR[8];
#pragma unroll
    for (int e = 0; e < 8; ++e) {
        scR[e] = sAux[fb + e];
        shR[e] = sAux[128 + fb + e];
    }

    f32x4 acc[3];
#pragma unroll
    for (int ni = 0; ni < 3; ++ni) {
        int feat = ni * 16 + l16;
        float bv = (feat < 36) ? bl[feat] : 0.f;
        acc[ni][0] = bv; acc[ni][1] = bv; acc[ni][2] = bv; acc[ni][3] = bv;
    }

    float4 av[8];
    f16x8 bv[3];

    auto issueA = [&](int j) {
#pragma unroll
        for (int it = 0; it < 4; ++it) {
            int nl = t16 + it * 16;
            int n = m0 + nl;
            n = (n < N) ? n : (N - 1);
            long row = idx[n * 7 + j];
            const float* src = &hprev[row * 128 + fb];
            av[2 * it]     = *(const float4*)src;
            av[2 * it + 1] = *(const float4*)(src + 4);
        }
    };
    auto issueB = [&](int j) {
#pragma unroll
        for (int it = 0; it < 3; ++it) {
            int ff = t16 + it * 16;
            bv[it] = *(const f16x8*)&WtF[(long)ff * 896 + j * 128 + fb];
        }
    };
    auto writeA = [&]() {
#pragma unroll
        for (int it = 0; it < 4; ++it) {
            int nl = t16 + it * 16;
            float4 v0 = av[2 * it], v1 = av[2 * it + 1];
            union { short sh8[8]; f16x8 v; } u;
            u.sh8[0] = f2h(fmaxf(fmaf(v0.x, scR[0], shR[0]), 0.f));
            u.sh8[1] = f2h(fmaxf(fmaf(v0.y, scR[1], shR[1]), 0.f));
            u.sh8[2] = f2h(fmaxf(fmaf(v0.z, scR[2], shR[2]), 0.f));
            u.sh8[3] = f2h(fmaxf(fmaf(v0.w, scR[3], shR[3]), 0.f));
            u.sh8[4] = f2h(fmaxf(fmaf(v1.x, scR[4], shR[4]), 0.f));
            u.sh8[5] = f2h(fmaxf(fmaf(v1.y, scR[5], shR[5]), 0.f));
            u.sh8[6] = f2h(fmaxf(fmaf(v1.z, scR[6], shR[6]), 0.f));
            u.sh8[7] = f2h(fmaxf(fmaf(v1.w, scR[7], shR[7]), 0.f));
            *(f16x8*)&sA[nl * 136 + fb] = u.v;
        }
    };
    auto writeB = [&]() {
#pragma unroll
        for (int it = 0; it < 3; ++it) {
            int ff = t16 + it * 16;
            *(f16x8*)&sB[ff * 136 + fb] = bv[it];
        }
    };

    issueB(0);
    issueA(0);

    for (int j = 0; j < 7; ++j) {
        __syncthreads();
        writeB();
        writeA();
        if (j < 6) {
            issueB(j + 1);
            issueA(j + 1);
        }
        __syncthreads();
#pragma unroll
        for (int k0 = 0; k0 < 128; k0 += 32) {
            f16x8 a = *(const f16x8*)&sA[(wave * 16 + l16) * 136 + k0 + quad * 8];
            f16x8 b[3];
#pragma unroll
            for (int ni = 0; ni < 3; ++ni)
                b[ni] = *(const f16x8*)&sB[(ni * 16 + l16) * 136 + k0 + quad * 8];
#pragma unroll
            for (int ni = 0; ni < 3; ++ni)
                acc[ni] = __builtin_amdgcn_mfma_f32_16x16x32_f16(a, b[ni], acc[ni], 0, 0, 0);
        }
    }

#pragma unroll
    for (int ni = 0; ni < 3; ++ni) {
        int feat = ni * 16 + l16;
        if (feat < 36) {
#pragma unroll
            for (int r = 0; r < 4; ++r) {
                int node = m0 + wave * 16 + quad * 4 + r;
                if (node < N) out[(long)node * 36 + feat] = acc[ni][r];
            }
        }
    }
}

// ---------------------------------------------------------------------------
extern "C" void kernel_launch(void* const* d_in, const int* in_sizes, int n_in,
                              void* d_out, int out_size, void* d_ws, size_t ws_size,
                              hipStream_t stream) {
    const float* x   = (const float*)d_in[0];
    const int*   idx = (const int*)d_in[1];
    const float* W0  = (const float*)d_in[2];
    const float* b0  = (const float*)d_in[3];
    const float* g0  = (const float*)d_in[4];
    const float* be0 = (const float*)d_in[5];
    const float* Wm  = (const float*)d_in[6];
    const float* bm  = (const float*)d_in[7];
    const float* gm  = (const float*)d_in[8];
    const float* bem = (const float*)d_in[9];
    const float* Wl  = (const float*)d_in[10];
    const float* bl  = (const float*)d_in[11];
    float* out = (float*)d_out;

    const int N = in_sizes[0] / 3;          // 40962
    const float invN = 1.0f / (float)N;

    char* ws = (char*)d_ws;
    size_t off = 0;
    auto alloc = [&](size_t bytes) -> void* {
        void* p = ws + off;
        off = (off + bytes + 255) & ~(size_t)255;
        return p;
    };
    short* WtM   = (short*)alloc(14UL * 128 * 896 * 2);
    short* WtF   = (short*)alloc(48UL * 896 * 2);
    float* stats = (float*)alloc(15UL * 256 * 4);
    float* hlinA = (float*)alloc((size_t)N * 128 * 4);
    float* hlinB = (float*)alloc((size_t)N * 128 * 4);

    {
        long total = 14L * 896 * 128 + 48L * 896 + 15L * 256;
        int blocks = (int)((total + 255) / 256);
        prep_kernel<<<blocks, 256, 0, stream>>>(Wm, Wl, WtM, WtF, stats);
    }

    layer0_kernel<<<1280, 256, 0, stream>>>(x, idx, W0, b0, hlinA, stats, N);

    const int gblocks = (N + 63) / 64;
    float* hin = hlinA;
    float* hout = hlinB;
    const float* gPrev = g0;
    const float* bePrev = be0;
    for (int L = 0; L < 14; ++L) {
        gemm_mid_kernel<<<gblocks, 256, 0, stream>>>(
            hin, idx, WtM + (size_t)L * 128 * 896, bm + L * 128,
            gPrev, bePrev, stats + L * 256,
            hout, stats + (L + 1) * 256, N, invN);
        gPrev = gm + L * 128;
        bePrev = bem + L * 128;
        float* t = hin; hin = hout; hout = t;
    }

    gemm_final_kernel<<<gblocks, 256, 0, stream>>>(
        hin, idx, WtF, bl, gm + 13 * 128, bem + 13 * 128, stats + 14 * 256,
        out, N, invN);
}